// Round 4
// baseline (974.200 us; speedup 1.0000x reference)
//
#include <hip/hip_runtime.h>
#include <hip/hip_bf16.h>
#include <math.h>

// ---------------------------------------------------------------------------
// TGCN: z/r/h GCN gates + GRU + readout.
// R1: segment_sum(w * (x@W)[src]) == segment_sum(w * x[src]) @ W
//     -> aggregate raw features ONCE (AX), fold W_g into Wl_g top half.
// R2: gate GEMMs on MFMA (bf16 in, f32 acc); weights pre-fused in d_ws.
// R3: packed bf16 atomics -> hit device atomic ceiling (125 dword-atomics/cy).
// R4: bucket-by-dst (256 nodes/bucket) + LDS f32 aggregation (ds_add_f32
//     scales per-CU: ~8192/cy device-wide vs 125/cy for global atomics).
//     hist -> scan -> reorder -> per-bucket LDS aggregate. Fallback to R3
//     atomic scatter if ws_size is too small.
// ---------------------------------------------------------------------------

typedef __attribute__((ext_vector_type(8))) short bf16x8;   // 8 bf16 = 4 VGPR
typedef __attribute__((ext_vector_type(4))) float f32x4;    // MFMA C/D

static __device__ __forceinline__ short f2bf(float x) {
    union { float f; unsigned u; } v; v.f = x;
    unsigned r = v.u + 0x7fffu + ((v.u >> 16) & 1u);        // RNE
    return (short)(r >> 16);
}
__device__ __forceinline__ float sigmoid_(float x) { return 1.0f / (1.0f + __expf(-x)); }
__device__ __forceinline__ float tanh_(float x)    { return 1.0f - 2.0f / (__expf(2.0f * x) + 1.0f); }

// xb = bf16(x); optionally AXb = 0 (fallback path); zero bucket counters
__global__ __launch_bounds__(256) void prep_kernel(
    const float* __restrict__ x, short* __restrict__ xb,
    short* __restrict__ AXb, int* __restrict__ cnt,
    int n8, int nbucket, int zeroAX)
{
    int gid = blockIdx.x * blockDim.x + threadIdx.x;
    if (gid < nbucket) cnt[gid] = 0;
    int stride = gridDim.x * blockDim.x;
    for (int i = gid; i < n8; i += stride) {
        float4 a = ((const float4*)x)[i * 2];
        float4 b = ((const float4*)x)[i * 2 + 1];
        bf16x8 v;
        v[0] = f2bf(a.x); v[1] = f2bf(a.y); v[2] = f2bf(a.z); v[3] = f2bf(a.w);
        v[4] = f2bf(b.x); v[5] = f2bf(b.y); v[6] = f2bf(b.z); v[7] = f2bf(b.w);
        ((bf16x8*)xb)[i] = v;
        if (zeroAX) {
            bf16x8 z = {0, 0, 0, 0, 0, 0, 0, 0};
            ((bf16x8*)AXb)[i] = z;
        }
    }
}

// count edges per 256-node dst bucket
__global__ __launch_bounds__(256) void hist_kernel(
    const int* __restrict__ ei, int* __restrict__ cnt, int E)
{
    int gid = blockIdx.x * blockDim.x + threadIdx.x;
    int stride = gridDim.x * blockDim.x;
    for (int i = gid; i < E; i += stride)
        atomicAdd(&cnt[ei[E + i] >> 8], 1);
}

// exclusive scan of cnt[NB] -> rowptr[NB+1], cursor[NB]   (single block, NB<=512)
__global__ __launch_bounds__(512) void scan_kernel(
    const int* __restrict__ cnt, int* __restrict__ rowptr,
    int* __restrict__ cursor, int NB)
{
    __shared__ int s[512];
    int t = threadIdx.x;
    s[t] = (t < NB) ? cnt[t] : 0;
    for (int off = 1; off < 512; off <<= 1) {
        __syncthreads();
        int v = (t >= off) ? s[t - off] : 0;
        __syncthreads();
        s[t] += v;
    }
    __syncthreads();
    int ex = t ? s[t - 1] : 0;
    if (t < NB) { rowptr[t] = ex; cursor[t] = ex; }
    if (t == NB) rowptr[NB] = s[NB - 1];
}

// scatter edges into bucket-contiguous slots: packed[p] = {src|dstLocal<<20, w}
__global__ __launch_bounds__(256) void reorder_kernel(
    const int* __restrict__ ei, const float* __restrict__ ew,
    int* __restrict__ cursor, uint2* __restrict__ packed, int E)
{
    int gid = blockIdx.x * blockDim.x + threadIdx.x;
    int stride = gridDim.x * blockDim.x;
    for (int i = gid; i < E; i += stride) {
        int src = ei[i];
        int dst = ei[E + i];
        float w = ew[i];
        int b = dst >> 8;
        int p = atomicAdd(&cursor[b], 1);
        packed[p] = make_uint2((unsigned)src | ((unsigned)(dst & 255) << 20),
                               __float_as_uint(w));
    }
}

// one workgroup per bucket: accumulate w*xb[src] into LDS f32, write AXb bf16.
__global__ __launch_bounds__(512) void aggregate_kernel(
    const short* __restrict__ xb, const uint2* __restrict__ packed,
    const int* __restrict__ rowptr, short* __restrict__ AXb, int N)
{
    __shared__ float acc[256 * 64];          // 64 KB
    const int tid = threadIdx.x;
    const int b   = blockIdx.x;

    const float4 z4 = make_float4(0.f, 0.f, 0.f, 0.f);
    for (int i = tid; i < 4096; i += 512) ((float4*)acc)[i] = z4;
    __syncthreads();

    const int start = rowptr[b], end = rowptr[b + 1];
    const int hw = tid >> 5;                 // 16 half-waves
    const int lj = tid & 31;                 // feature pair
    for (int e = start + hw; e < end; e += 16) {
        uint2 m = packed[e];
        int src = m.x & 0xFFFFF;
        int dl  = m.x >> 20;
        float w = __uint_as_float(m.y);
        unsigned pv = *(const unsigned*)(xb + (size_t)src * 64 + lj * 2);
        float lo = __uint_as_float(pv << 16) * w;
        float hi = __uint_as_float(pv & 0xffff0000u) * w;
        atomicAdd(&acc[dl * 64 + lj * 2],     lo);
        atomicAdd(&acc[dl * 64 + lj * 2 + 1], hi);
    }
    __syncthreads();

    const int nl = tid >> 1;
    const int c0 = (tid & 1) * 32;
    const int n  = b * 256 + nl;
    if (n < N) {
#pragma unroll
        for (int q = 0; q < 4; q++) {
            const float* p = &acc[nl * 64 + c0 + q * 8];
            bf16x8 v;
#pragma unroll
            for (int j = 0; j < 8; j++) v[j] = f2bf(p[j]);
            *(bf16x8*)(AXb + (size_t)n * 64 + c0 + q * 8) = v;
        }
    }
}

// ---- R3 fallback: packed bf16 global atomics --------------------------------
__global__ __launch_bounds__(256) void scatter_kernel(
    const short* __restrict__ xb, const float* __restrict__ ew,
    const int* __restrict__ ei, short* __restrict__ AXb, int E)
{
    int hw  = (blockIdx.x * 256 + threadIdx.x) >> 5;
    int lj  = threadIdx.x & 31;
    int nhw = (gridDim.x * 256) >> 5;
    for (int e = hw; e < E; e += nhw) {
        int src = ei[e];
        int dst = ei[E + e];
        float w = ew[e];
        unsigned pv = *(const unsigned*)(xb + (size_t)src * 64 + lj * 2);
        float lo = __uint_as_float(pv << 16) * w;
        float hi = __uint_as_float(pv & 0xffff0000u) * w;
        unsigned pk = (unsigned)(unsigned short)f2bf(lo)
                    | ((unsigned)(unsigned short)f2bf(hi) << 16);
        short* addr = AXb + (size_t)dst * 64 + lj * 2;
        asm volatile("global_atomic_pk_add_bf16 %0, %1, off"
                     :: "v"(addr), "v"(pk) : "memory");
    }
    asm volatile("s_waitcnt vmcnt(0)" ::: "memory");
}

// Produces, in d_ws:
//   WT[m][64][64] bf16, n-major (transposed), m = 0..6:
//     0..2 : W_g @ Wl_g_top ; 3..5 : Wl_g_bottom ; 6 : W_out
//   bfv[4][64] f32: fused biases
__global__ __launch_bounds__(256) void fuse_weights_kernel(
    const float* __restrict__ Wz, const float* __restrict__ Wr, const float* __restrict__ Wh,
    const float* __restrict__ bz, const float* __restrict__ br, const float* __restrict__ bh,
    const float* __restrict__ Wlz, const float* __restrict__ Wlr, const float* __restrict__ Wlh,
    const float* __restrict__ blz, const float* __restrict__ blr, const float* __restrict__ blh,
    const float* __restrict__ Wout, const float* __restrict__ bout_,
    short* __restrict__ WT, float* __restrict__ bfv)
{
    int g = blockIdx.x;
    int tid = threadIdx.x;
    if (g == 3) {
        for (int i = tid; i < 4096; i += 256) {
            int k = i >> 6, n = i & 63;
            WT[6 * 4096 + n * 64 + k] = f2bf(Wout[k * 64 + n]);
        }
        if (tid < 64) bfv[192 + tid] = bout_[tid];
        return;
    }
    const float* Win = (g == 0) ? Wz : (g == 1) ? Wr : Wh;
    const float* Wl  = (g == 0) ? Wlz : (g == 1) ? Wlr : Wlh;
    const float* b   = (g == 0) ? bz : (g == 1) ? br : bh;
    const float* bl  = (g == 0) ? blz : (g == 1) ? blr : blh;

    __shared__ float wl_s[64][65];
    for (int i = tid; i < 4096; i += 256) wl_s[i >> 6][i & 63] = Wl[i];
    __syncthreads();

    int k = tid >> 2;
    int j0 = (tid & 3) << 4;
    float acc[16];
#pragma unroll
    for (int jj = 0; jj < 16; jj++) acc[jj] = 0.f;
    for (int t = 0; t < 64; t++) {
        float a = Win[k * 64 + t];
#pragma unroll
        for (int jj = 0; jj < 16; jj++) acc[jj] = fmaf(a, wl_s[t][j0 + jj], acc[jj]);
    }
#pragma unroll
    for (int jj = 0; jj < 16; jj++) WT[g * 4096 + (j0 + jj) * 64 + k] = f2bf(acc[jj]);

    for (int i = tid; i < 4096; i += 256) {
        int kk = i >> 6, n = i & 63;
        WT[(3 + g) * 4096 + n * 64 + kk] = f2bf(Wl[(64 + kk) * 64 + n]);
    }
    if (tid < 64) {
        float a2 = bl[tid];
        for (int t = 0; t < 64; t++) a2 = fmaf(b[t], wl_s[t][tid], a2);
        bfv[g * 64 + tid] = a2;
    }
}

// Fused GRU gates + readout via MFMA. 64-node tile, 4 waves.
__global__ __launch_bounds__(256, 3) void gates_kernel(
    const short* __restrict__ AXb, const float* __restrict__ hid,
    const short* __restrict__ WT, const float* __restrict__ bfv,
    float* __restrict__ outY, float* __restrict__ outH, int nNodes)
{
    __shared__ short axs[64][72];
    __shared__ short hs [64][72];
    __shared__ short rsb[64][72];
    __shared__ float hf [64][68];

    const int tid  = threadIdx.x;
    const int w    = tid >> 6;
    const int lane = tid & 63;
    const int lr   = lane & 15;
    const int lg   = lane >> 4;
    const int col  = w * 16 + lr;
    const int n0   = blockIdx.x * 64;

    {
        int row = tid >> 2;
        int c0  = (tid & 3) << 4;
        int n   = n0 + row;
        bool valid = n < nNodes;
        const float4 z4 = make_float4(0.f, 0.f, 0.f, 0.f);
        const bf16x8 zb = {0, 0, 0, 0, 0, 0, 0, 0};
        bf16x8 a0 = valid ? *(const bf16x8*)(AXb + (size_t)n * 64 + c0)     : zb;
        bf16x8 a1 = valid ? *(const bf16x8*)(AXb + (size_t)n * 64 + c0 + 8) : zb;
        *(bf16x8*)(&axs[row][c0])     = a0;
        *(bf16x8*)(&axs[row][c0 + 8]) = a1;
#pragma unroll
        for (int q = 0; q < 4; q++) {
            float4 vh = valid ? *(const float4*)(hid + (size_t)n * 64 + c0 + q * 4) : z4;
            int c = c0 + q * 4;
            hs[row][c + 0] = f2bf(vh.x); hs[row][c + 1] = f2bf(vh.y);
            hs[row][c + 2] = f2bf(vh.z); hs[row][c + 3] = f2bf(vh.w);
            hf[row][c + 0] = vh.x; hf[row][c + 1] = vh.y;
            hf[row][c + 2] = vh.z; hf[row][c + 3] = vh.w;
        }
    }

    bf16x8 wf[7][2];
#pragma unroll
    for (int m = 0; m < 7; m++)
#pragma unroll
        for (int kb = 0; kb < 2; kb++)
            wf[m][kb] = *(const bf16x8*)(WT + m * 4096 + col * 64 + kb * 32 + lg * 8);
    const float bz_ = bfv[col], br_ = bfv[64 + col], bh_ = bfv[128 + col], bo_ = bfv[192 + col];

    __syncthreads();

    const f32x4 zero4 = {0.f, 0.f, 0.f, 0.f};
    f32x4 accz[4], accr[4], acch[4];
#pragma unroll
    for (int rt = 0; rt < 4; rt++) { accz[rt] = zero4; accr[rt] = zero4; acch[rt] = zero4; }

#pragma unroll
    for (int rt = 0; rt < 4; rt++) {
        int arow = rt * 16 + lr;
#pragma unroll
        for (int kb = 0; kb < 2; kb++) {
            bf16x8 aa = *(const bf16x8*)(&axs[arow][kb * 32 + lg * 8]);
            bf16x8 ah = *(const bf16x8*)(&hs [arow][kb * 32 + lg * 8]);
            accz[rt] = __builtin_amdgcn_mfma_f32_16x16x32_bf16(aa, wf[0][kb], accz[rt], 0, 0, 0);
            accr[rt] = __builtin_amdgcn_mfma_f32_16x16x32_bf16(aa, wf[1][kb], accr[rt], 0, 0, 0);
            acch[rt] = __builtin_amdgcn_mfma_f32_16x16x32_bf16(aa, wf[2][kb], acch[rt], 0, 0, 0);
            accz[rt] = __builtin_amdgcn_mfma_f32_16x16x32_bf16(ah, wf[3][kb], accz[rt], 0, 0, 0);
            accr[rt] = __builtin_amdgcn_mfma_f32_16x16x32_bf16(ah, wf[4][kb], accr[rt], 0, 0, 0);
        }
    }

    float zf[16];
#pragma unroll
    for (int rt = 0; rt < 4; rt++) {
#pragma unroll
        for (int i = 0; i < 4; i++) {
            int row = rt * 16 + lg * 4 + i;
            float z = sigmoid_(accz[rt][i] + bz_);
            float r = sigmoid_(accr[rt][i] + br_);
            zf[rt * 4 + i] = z;
            rsb[row][col] = f2bf(r * hf[row][col]);
        }
    }
    __syncthreads();

#pragma unroll
    for (int rt = 0; rt < 4; rt++) {
        int arow = rt * 16 + lr;
#pragma unroll
        for (int kb = 0; kb < 2; kb++) {
            bf16x8 ar = *(const bf16x8*)(&rsb[arow][kb * 32 + lg * 8]);
            acch[rt] = __builtin_amdgcn_mfma_f32_16x16x32_bf16(ar, wf[5][kb], acch[rt], 0, 0, 0);
        }
    }
#pragma unroll
    for (int rt = 0; rt < 4; rt++) {
#pragma unroll
        for (int i = 0; i < 4; i++) {
            int row = rt * 16 + lg * 4 + i;
            float ht = tanh_(acch[rt][i] + bh_);
            float z  = zf[rt * 4 + i];
            float hv = z * hf[row][col] + (1.f - z) * ht;
            int n = n0 + row;
            if (n < nNodes) outH[(size_t)n * 64 + col] = hv;
            axs[row][col] = f2bf(fmaxf(hv, 0.f));
        }
    }
    __syncthreads();

    f32x4 accy[4];
#pragma unroll
    for (int rt = 0; rt < 4; rt++) accy[rt] = zero4;
#pragma unroll
    for (int rt = 0; rt < 4; rt++) {
        int arow = rt * 16 + lr;
#pragma unroll
        for (int kb = 0; kb < 2; kb++) {
            bf16x8 aa = *(const bf16x8*)(&axs[arow][kb * 32 + lg * 8]);
            accy[rt] = __builtin_amdgcn_mfma_f32_16x16x32_bf16(aa, wf[6][kb], accy[rt], 0, 0, 0);
        }
    }
#pragma unroll
    for (int rt = 0; rt < 4; rt++) {
#pragma unroll
        for (int i = 0; i < 4; i++) {
            int row = rt * 16 + lg * 4 + i;
            int n = n0 + row;
            if (n < nNodes) outY[(size_t)n * 64 + col] = accy[rt][i] + bo_;
        }
    }
}

extern "C" void kernel_launch(void* const* d_in, const int* in_sizes, int n_in,
                              void* d_out, int out_size, void* d_ws, size_t ws_size,
                              hipStream_t stream)
{
    const float* node_feat = (const float*)d_in[0];
    const float* edge_w    = (const float*)d_in[1];
    const float* hidden    = (const float*)d_in[2];
    const float* W_z  = (const float*)d_in[3];
    const float* b_z  = (const float*)d_in[4];
    const float* W_r  = (const float*)d_in[5];
    const float* b_r  = (const float*)d_in[6];
    const float* W_h  = (const float*)d_in[7];
    const float* b_h  = (const float*)d_in[8];
    const float* Wl_z = (const float*)d_in[9];
    const float* bl_z = (const float*)d_in[10];
    const float* Wl_r = (const float*)d_in[11];
    const float* bl_r = (const float*)d_in[12];
    const float* Wl_h = (const float*)d_in[13];
    const float* bl_h = (const float*)d_in[14];
    const float* W_out = (const float*)d_in[15];
    const float* b_out = (const float*)d_in[16];
    const int*   edge_index = (const int*)d_in[17];

    const int N = in_sizes[0] / 64;
    const int E = in_sizes[1];
    const int NB = (N + 255) >> 8;

    char* ws = (char*)d_ws;
    size_t off = 0;
    short* AXb = (short*)(ws + off); off += (size_t)N * 64 * 2;
    short* xb  = (short*)(ws + off); off += (size_t)N * 64 * 2;
    short* WT  = (short*)(ws + off); off += 7 * 4096 * 2;
    float* bfv = (float*)(ws + off); off += 4 * 64 * 4;
    int* cnt    = (int*)(ws + off);  off += (size_t)NB * 4;
    int* rowptr = (int*)(ws + off);  off += (size_t)(NB + 1) * 4;
    int* cursor = (int*)(ws + off);  off += (size_t)NB * 4;
    off = (off + 7) & ~(size_t)7;
    uint2* packed = (uint2*)(ws + off); off += (size_t)E * 8;

    const bool useCSR = (ws_size >= off) && (NB <= 512);

    float* outY = (float*)d_out;                 // [N,64]
    float* outH = outY + (size_t)N * 64;         // [N,64]

    fuse_weights_kernel<<<4, 256, 0, stream>>>(W_z, W_r, W_h, b_z, b_r, b_h,
                                               Wl_z, Wl_r, Wl_h, bl_z, bl_r, bl_h,
                                               W_out, b_out, WT, bfv);
    if (useCSR) {
        prep_kernel<<<1024, 256, 0, stream>>>(node_feat, xb, AXb, cnt, N * 8, NB, 0);
        hist_kernel<<<1024, 256, 0, stream>>>(edge_index, cnt, E);
        scan_kernel<<<1, 512, 0, stream>>>(cnt, rowptr, cursor, NB);
        reorder_kernel<<<1024, 256, 0, stream>>>(edge_index, edge_w, cursor, packed, E);
        aggregate_kernel<<<NB, 512, 0, stream>>>(xb, packed, rowptr, AXb, N);
    } else {
        prep_kernel<<<1024, 256, 0, stream>>>(node_feat, xb, AXb, cnt, N * 8, 0, 1);
        scatter_kernel<<<2048, 256, 0, stream>>>(xb, edge_w, edge_index, AXb, E);
    }

    int nblk = (N + 63) / 64;
    gates_kernel<<<nblk, 256, 0, stream>>>(AXb, hidden, WT, bfv, outY, outH, N);
}

// Round 5
// 198.055 us; speedup vs baseline: 4.9188x; 4.9188x over previous
//
#include <hip/hip_runtime.h>
#include <hip/hip_bf16.h>
#include <math.h>

// ---------------------------------------------------------------------------
// TGCN: z/r/h GCN gates + GRU + readout.
// R1: segment_sum(w * (x@W)[src]) == segment_sum(w * x[src]) @ W
//     -> aggregate raw features ONCE (AX), fold W_g into Wl_g top half.
// R2: gate GEMMs on MFMA (bf16 in, f32 acc); weights pre-fused in d_ws.
// R3: packed bf16 atomics -> hit device atomic ceiling (125 dword-atomics/cy).
// R4: bucket-LDS aggregation FAILED: 64KB LDS -> 2 blk/CU, 24% occ,
//     latency-bound (VALU 2.3%). Lesson: keep occupancy high, avoid LDS caps.
// R5: full per-node CSR (hist -> block scan -> reorder) + register-accumulate
//     aggregate: one half-wave per node, f32 regs, ZERO hot-loop atomics,
//     no LDS -> full occupancy. Fallback to R3 scatter if ws too small.
// ---------------------------------------------------------------------------

typedef __attribute__((ext_vector_type(8))) short bf16x8;   // 8 bf16 = 4 VGPR
typedef __attribute__((ext_vector_type(4))) float f32x4;    // MFMA C/D

static __device__ __forceinline__ short f2bf(float x) {
    union { float f; unsigned u; } v; v.f = x;
    unsigned r = v.u + 0x7fffu + ((v.u >> 16) & 1u);        // RNE
    return (short)(r >> 16);
}
__device__ __forceinline__ float sigmoid_(float x) { return 1.0f / (1.0f + __expf(-x)); }
__device__ __forceinline__ float tanh_(float x)    { return 1.0f - 2.0f / (__expf(2.0f * x) + 1.0f); }

// xb = bf16(x); zero cnt[ncnt]; optionally zero AXb (fallback path)
__global__ __launch_bounds__(256) void prep_kernel(
    const float* __restrict__ x, short* __restrict__ xb,
    short* __restrict__ AXb, int* __restrict__ cnt,
    int n8, int ncnt, int zeroAX)
{
    int gid = blockIdx.x * blockDim.x + threadIdx.x;
    int stride = gridDim.x * blockDim.x;
    for (int i = gid; i < ncnt; i += stride) cnt[i] = 0;
    for (int i = gid; i < n8; i += stride) {
        float4 a = ((const float4*)x)[i * 2];
        float4 b = ((const float4*)x)[i * 2 + 1];
        bf16x8 v;
        v[0] = f2bf(a.x); v[1] = f2bf(a.y); v[2] = f2bf(a.z); v[3] = f2bf(a.w);
        v[4] = f2bf(b.x); v[5] = f2bf(b.y); v[6] = f2bf(b.z); v[7] = f2bf(b.w);
        ((bf16x8*)xb)[i] = v;
        if (zeroAX) {
            bf16x8 z = {0, 0, 0, 0, 0, 0, 0, 0};
            ((bf16x8*)AXb)[i] = z;
        }
    }
}

// count edges per dst node (atomics spread over N addresses, ~deg per addr)
__global__ __launch_bounds__(256) void hist_kernel(
    const int* __restrict__ ei, int* __restrict__ cnt, int E)
{
    int gid = blockIdx.x * blockDim.x + threadIdx.x;
    int stride = gridDim.x * blockDim.x;
    for (int i = gid; i < E; i += stride)
        atomicAdd(&cnt[ei[E + i]], 1);
}

// per-block (2048-elem) exclusive scan of cnt -> rowptr, block totals -> blksum
__global__ __launch_bounds__(256) void scan_blk_kernel(
    const int* __restrict__ cnt, int* __restrict__ rowptr,
    int* __restrict__ blksum, int N)
{
    __shared__ int s[256];
    int t = threadIdx.x;
    int base = blockIdx.x * 2048 + t * 8;
    int v[8]; int sum = 0;
#pragma unroll
    for (int j = 0; j < 8; j++) {
        int idx = base + j;
        v[j] = (idx < N) ? cnt[idx] : 0;
        sum += v[j];
    }
    s[t] = sum;
    for (int off = 1; off < 256; off <<= 1) {
        __syncthreads();
        int x = (t >= off) ? s[t - off] : 0;
        __syncthreads();
        s[t] += x;
    }
    __syncthreads();
    int ex = (t > 0) ? s[t - 1] : 0;
#pragma unroll
    for (int j = 0; j < 8; j++) {
        int idx = base + j;
        if (idx < N) rowptr[idx] = ex;
        ex += v[j];
    }
    if (t == 255) blksum[blockIdx.x] = s[255];
}

// add block offsets in place; init cursor; write rowptr[N] = E
__global__ __launch_bounds__(256) void scan_fix_kernel(
    int* __restrict__ rowptr, int* __restrict__ cursor,
    const int* __restrict__ blksum, int N, int E)
{
    __shared__ int off_s;
    int t = threadIdx.x;
    if (t == 0) {
        int a = 0;
        for (int i = 0; i < (int)blockIdx.x; i++) a += blksum[i];
        off_s = a;
    }
    __syncthreads();
    int offv = off_s;
    int base = blockIdx.x * 2048 + t * 8;
#pragma unroll
    for (int j = 0; j < 8; j++) {
        int idx = base + j;
        if (idx < N) { int r = rowptr[idx] + offv; rowptr[idx] = r; cursor[idx] = r; }
    }
    if (base <= N && N < base + 8) rowptr[N] = E;   // covered by some block
}

// scatter edges into dst-contiguous slots: packed[p] = {src, w}
__global__ __launch_bounds__(256) void reorder_kernel(
    const int* __restrict__ ei, const float* __restrict__ ew,
    int* __restrict__ cursor, uint2* __restrict__ packed, int E)
{
    int gid = blockIdx.x * blockDim.x + threadIdx.x;
    int stride = gridDim.x * blockDim.x;
    for (int i = gid; i < E; i += stride) {
        int src = ei[i];
        int dst = ei[E + i];
        float w = ew[i];
        int p = atomicAdd(&cursor[dst], 1);
        packed[p] = make_uint2((unsigned)src, __float_as_uint(w));
    }
}

// one half-wave per node: f32 register accumulation, no atomics, no LDS.
__global__ __launch_bounds__(512) void aggregate_csr_kernel(
    const short* __restrict__ xb, const uint2* __restrict__ packed,
    const int* __restrict__ rowptr, short* __restrict__ AXb, int N)
{
    int hw = (blockIdx.x * 512 + threadIdx.x) >> 5;   // node id
    int lj = threadIdx.x & 31;                        // feature pair
    if (hw >= N) return;
    int s = rowptr[hw], e0 = rowptr[hw + 1];
    float a0 = 0.f, a1 = 0.f;
    int e = s;
    for (; e + 1 < e0; e += 2) {                      // 2-way unroll for MLP
        uint2 m0 = packed[e], m1 = packed[e + 1];
        unsigned p0 = *(const unsigned*)(xb + (size_t)m0.x * 64 + lj * 2);
        unsigned p1 = *(const unsigned*)(xb + (size_t)m1.x * 64 + lj * 2);
        float w0 = __uint_as_float(m0.y), w1 = __uint_as_float(m1.y);
        a0 = fmaf(__uint_as_float(p0 << 16),         w0, a0);
        a1 = fmaf(__uint_as_float(p0 & 0xffff0000u), w0, a1);
        a0 = fmaf(__uint_as_float(p1 << 16),         w1, a0);
        a1 = fmaf(__uint_as_float(p1 & 0xffff0000u), w1, a1);
    }
    if (e < e0) {
        uint2 m = packed[e];
        unsigned pv = *(const unsigned*)(xb + (size_t)m.x * 64 + lj * 2);
        float w = __uint_as_float(m.y);
        a0 = fmaf(__uint_as_float(pv << 16),         w, a0);
        a1 = fmaf(__uint_as_float(pv & 0xffff0000u), w, a1);
    }
    unsigned pk = (unsigned)(unsigned short)f2bf(a0)
                | ((unsigned)(unsigned short)f2bf(a1) << 16);
    *(unsigned*)(AXb + (size_t)hw * 64 + lj * 2) = pk;
}

// ---- R3 fallback: packed bf16 global atomics --------------------------------
__global__ __launch_bounds__(256) void scatter_kernel(
    const short* __restrict__ xb, const float* __restrict__ ew,
    const int* __restrict__ ei, short* __restrict__ AXb, int E)
{
    int hw  = (blockIdx.x * 256 + threadIdx.x) >> 5;
    int lj  = threadIdx.x & 31;
    int nhw = (gridDim.x * 256) >> 5;
    for (int e = hw; e < E; e += nhw) {
        int src = ei[e];
        int dst = ei[E + e];
        float w = ew[e];
        unsigned pv = *(const unsigned*)(xb + (size_t)src * 64 + lj * 2);
        float lo = __uint_as_float(pv << 16) * w;
        float hi = __uint_as_float(pv & 0xffff0000u) * w;
        unsigned pk = (unsigned)(unsigned short)f2bf(lo)
                    | ((unsigned)(unsigned short)f2bf(hi) << 16);
        short* addr = AXb + (size_t)dst * 64 + lj * 2;
        asm volatile("global_atomic_pk_add_bf16 %0, %1, off"
                     :: "v"(addr), "v"(pk) : "memory");
    }
    asm volatile("s_waitcnt vmcnt(0)" ::: "memory");
}

// Produces, in d_ws:
//   WT[m][64][64] bf16, n-major (transposed), m = 0..6:
//     0..2 : W_g @ Wl_g_top ; 3..5 : Wl_g_bottom ; 6 : W_out
//   bfv[4][64] f32: fused biases
__global__ __launch_bounds__(256) void fuse_weights_kernel(
    const float* __restrict__ Wz, const float* __restrict__ Wr, const float* __restrict__ Wh,
    const float* __restrict__ bz, const float* __restrict__ br, const float* __restrict__ bh,
    const float* __restrict__ Wlz, const float* __restrict__ Wlr, const float* __restrict__ Wlh,
    const float* __restrict__ blz, const float* __restrict__ blr, const float* __restrict__ blh,
    const float* __restrict__ Wout, const float* __restrict__ bout_,
    short* __restrict__ WT, float* __restrict__ bfv)
{
    int g = blockIdx.x;
    int tid = threadIdx.x;
    if (g == 3) {
        for (int i = tid; i < 4096; i += 256) {
            int k = i >> 6, n = i & 63;
            WT[6 * 4096 + n * 64 + k] = f2bf(Wout[k * 64 + n]);
        }
        if (tid < 64) bfv[192 + tid] = bout_[tid];
        return;
    }
    const float* Win = (g == 0) ? Wz : (g == 1) ? Wr : Wh;
    const float* Wl  = (g == 0) ? Wlz : (g == 1) ? Wlr : Wlh;
    const float* b   = (g == 0) ? bz : (g == 1) ? br : bh;
    const float* bl  = (g == 0) ? blz : (g == 1) ? blr : blh;

    __shared__ float wl_s[64][65];
    for (int i = tid; i < 4096; i += 256) wl_s[i >> 6][i & 63] = Wl[i];
    __syncthreads();

    int k = tid >> 2;
    int j0 = (tid & 3) << 4;
    float acc[16];
#pragma unroll
    for (int jj = 0; jj < 16; jj++) acc[jj] = 0.f;
    for (int t = 0; t < 64; t++) {
        float a = Win[k * 64 + t];
#pragma unroll
        for (int jj = 0; jj < 16; jj++) acc[jj] = fmaf(a, wl_s[t][j0 + jj], acc[jj]);
    }
#pragma unroll
    for (int jj = 0; jj < 16; jj++) WT[g * 4096 + (j0 + jj) * 64 + k] = f2bf(acc[jj]);

    for (int i = tid; i < 4096; i += 256) {
        int kk = i >> 6, n = i & 63;
        WT[(3 + g) * 4096 + n * 64 + kk] = f2bf(Wl[(64 + kk) * 64 + n]);
    }
    if (tid < 64) {
        float a2 = bl[tid];
        for (int t = 0; t < 64; t++) a2 = fmaf(b[t], wl_s[t][tid], a2);
        bfv[g * 64 + tid] = a2;
    }
}

// Fused GRU gates + readout via MFMA. 64-node tile, 4 waves.
__global__ __launch_bounds__(256, 3) void gates_kernel(
    const short* __restrict__ AXb, const float* __restrict__ hid,
    const short* __restrict__ WT, const float* __restrict__ bfv,
    float* __restrict__ outY, float* __restrict__ outH, int nNodes)
{
    __shared__ short axs[64][72];
    __shared__ short hs [64][72];
    __shared__ short rsb[64][72];
    __shared__ float hf [64][68];

    const int tid  = threadIdx.x;
    const int w    = tid >> 6;
    const int lane = tid & 63;
    const int lr   = lane & 15;
    const int lg   = lane >> 4;
    const int col  = w * 16 + lr;
    const int n0   = blockIdx.x * 64;

    {
        int row = tid >> 2;
        int c0  = (tid & 3) << 4;
        int n   = n0 + row;
        bool valid = n < nNodes;
        const float4 z4 = make_float4(0.f, 0.f, 0.f, 0.f);
        const bf16x8 zb = {0, 0, 0, 0, 0, 0, 0, 0};
        bf16x8 a0 = valid ? *(const bf16x8*)(AXb + (size_t)n * 64 + c0)     : zb;
        bf16x8 a1 = valid ? *(const bf16x8*)(AXb + (size_t)n * 64 + c0 + 8) : zb;
        *(bf16x8*)(&axs[row][c0])     = a0;
        *(bf16x8*)(&axs[row][c0 + 8]) = a1;
#pragma unroll
        for (int q = 0; q < 4; q++) {
            float4 vh = valid ? *(const float4*)(hid + (size_t)n * 64 + c0 + q * 4) : z4;
            int c = c0 + q * 4;
            hs[row][c + 0] = f2bf(vh.x); hs[row][c + 1] = f2bf(vh.y);
            hs[row][c + 2] = f2bf(vh.z); hs[row][c + 3] = f2bf(vh.w);
            hf[row][c + 0] = vh.x; hf[row][c + 1] = vh.y;
            hf[row][c + 2] = vh.z; hf[row][c + 3] = vh.w;
        }
    }

    bf16x8 wf[7][2];
#pragma unroll
    for (int m = 0; m < 7; m++)
#pragma unroll
        for (int kb = 0; kb < 2; kb++)
            wf[m][kb] = *(const bf16x8*)(WT + m * 4096 + col * 64 + kb * 32 + lg * 8);
    const float bz_ = bfv[col], br_ = bfv[64 + col], bh_ = bfv[128 + col], bo_ = bfv[192 + col];

    __syncthreads();

    const f32x4 zero4 = {0.f, 0.f, 0.f, 0.f};
    f32x4 accz[4], accr[4], acch[4];
#pragma unroll
    for (int rt = 0; rt < 4; rt++) { accz[rt] = zero4; accr[rt] = zero4; acch[rt] = zero4; }

#pragma unroll
    for (int rt = 0; rt < 4; rt++) {
        int arow = rt * 16 + lr;
#pragma unroll
        for (int kb = 0; kb < 2; kb++) {
            bf16x8 aa = *(const bf16x8*)(&axs[arow][kb * 32 + lg * 8]);
            bf16x8 ah = *(const bf16x8*)(&hs [arow][kb * 32 + lg * 8]);
            accz[rt] = __builtin_amdgcn_mfma_f32_16x16x32_bf16(aa, wf[0][kb], accz[rt], 0, 0, 0);
            accr[rt] = __builtin_amdgcn_mfma_f32_16x16x32_bf16(aa, wf[1][kb], accr[rt], 0, 0, 0);
            acch[rt] = __builtin_amdgcn_mfma_f32_16x16x32_bf16(aa, wf[2][kb], acch[rt], 0, 0, 0);
            accz[rt] = __builtin_amdgcn_mfma_f32_16x16x32_bf16(ah, wf[3][kb], accz[rt], 0, 0, 0);
            accr[rt] = __builtin_amdgcn_mfma_f32_16x16x32_bf16(ah, wf[4][kb], accr[rt], 0, 0, 0);
        }
    }

    float zf[16];
#pragma unroll
    for (int rt = 0; rt < 4; rt++) {
#pragma unroll
        for (int i = 0; i < 4; i++) {
            int row = rt * 16 + lg * 4 + i;
            float z = sigmoid_(accz[rt][i] + bz_);
            float r = sigmoid_(accr[rt][i] + br_);
            zf[rt * 4 + i] = z;
            rsb[row][col] = f2bf(r * hf[row][col]);
        }
    }
    __syncthreads();

#pragma unroll
    for (int rt = 0; rt < 4; rt++) {
        int arow = rt * 16 + lr;
#pragma unroll
        for (int kb = 0; kb < 2; kb++) {
            bf16x8 ar = *(const bf16x8*)(&rsb[arow][kb * 32 + lg * 8]);
            acch[rt] = __builtin_amdgcn_mfma_f32_16x16x32_bf16(ar, wf[5][kb], acch[rt], 0, 0, 0);
        }
    }
#pragma unroll
    for (int rt = 0; rt < 4; rt++) {
#pragma unroll
        for (int i = 0; i < 4; i++) {
            int row = rt * 16 + lg * 4 + i;
            float ht = tanh_(acch[rt][i] + bh_);
            float z  = zf[rt * 4 + i];
            float hv = z * hf[row][col] + (1.f - z) * ht;
            int n = n0 + row;
            if (n < nNodes) outH[(size_t)n * 64 + col] = hv;
            axs[row][col] = f2bf(fmaxf(hv, 0.f));
        }
    }
    __syncthreads();

    f32x4 accy[4];
#pragma unroll
    for (int rt = 0; rt < 4; rt++) accy[rt] = zero4;
#pragma unroll
    for (int rt = 0; rt < 4; rt++) {
        int arow = rt * 16 + lr;
#pragma unroll
        for (int kb = 0; kb < 2; kb++) {
            bf16x8 aa = *(const bf16x8*)(&axs[arow][kb * 32 + lg * 8]);
            accy[rt] = __builtin_amdgcn_mfma_f32_16x16x32_bf16(aa, wf[6][kb], accy[rt], 0, 0, 0);
        }
    }
#pragma unroll
    for (int rt = 0; rt < 4; rt++) {
#pragma unroll
        for (int i = 0; i < 4; i++) {
            int row = rt * 16 + lg * 4 + i;
            int n = n0 + row;
            if (n < nNodes) outY[(size_t)n * 64 + col] = accy[rt][i] + bo_;
        }
    }
}

extern "C" void kernel_launch(void* const* d_in, const int* in_sizes, int n_in,
                              void* d_out, int out_size, void* d_ws, size_t ws_size,
                              hipStream_t stream)
{
    const float* node_feat = (const float*)d_in[0];
    const float* edge_w    = (const float*)d_in[1];
    const float* hidden    = (const float*)d_in[2];
    const float* W_z  = (const float*)d_in[3];
    const float* b_z  = (const float*)d_in[4];
    const float* W_r  = (const float*)d_in[5];
    const float* b_r  = (const float*)d_in[6];
    const float* W_h  = (const float*)d_in[7];
    const float* b_h  = (const float*)d_in[8];
    const float* Wl_z = (const float*)d_in[9];
    const float* bl_z = (const float*)d_in[10];
    const float* Wl_r = (const float*)d_in[11];
    const float* bl_r = (const float*)d_in[12];
    const float* Wl_h = (const float*)d_in[13];
    const float* bl_h = (const float*)d_in[14];
    const float* W_out = (const float*)d_in[15];
    const float* b_out = (const float*)d_in[16];
    const int*   edge_index = (const int*)d_in[17];

    const int N = in_sizes[0] / 64;
    const int E = in_sizes[1];
    const int NBLK = (N + 2047) / 2048;

    char* ws = (char*)d_ws;
    size_t off = 0;
    short* AXb = (short*)(ws + off); off += (size_t)N * 64 * 2;
    short* xb  = (short*)(ws + off); off += (size_t)N * 64 * 2;
    short* WT  = (short*)(ws + off); off += 7 * 4096 * 2;
    float* bfv = (float*)(ws + off); off += 4 * 64 * 4;
    int* cnt    = (int*)(ws + off);  off += (size_t)N * 4;
    int* rowptr = (int*)(ws + off);  off += (size_t)(N + 1) * 4;
    int* cursor = (int*)(ws + off);  off += (size_t)N * 4;
    int* blksum = (int*)(ws + off);  off += (size_t)NBLK * 4;
    off = (off + 7) & ~(size_t)7;
    uint2* packed = (uint2*)(ws + off); off += (size_t)E * 8;

    const bool useCSR = (ws_size >= off);

    float* outY = (float*)d_out;                 // [N,64]
    float* outH = outY + (size_t)N * 64;         // [N,64]

    fuse_weights_kernel<<<4, 256, 0, stream>>>(W_z, W_r, W_h, b_z, b_r, b_h,
                                               Wl_z, Wl_r, Wl_h, bl_z, bl_r, bl_h,
                                               W_out, b_out, WT, bfv);
    if (useCSR) {
        prep_kernel<<<1024, 256, 0, stream>>>(node_feat, xb, AXb, cnt, N * 8, N, 0);
        hist_kernel<<<1024, 256, 0, stream>>>(edge_index, cnt, E);
        scan_blk_kernel<<<NBLK, 256, 0, stream>>>(cnt, rowptr, blksum, N);
        scan_fix_kernel<<<NBLK, 256, 0, stream>>>(rowptr, cursor, blksum, N, E);
        reorder_kernel<<<1024, 256, 0, stream>>>(edge_index, edge_w, cursor, packed, E);
        aggregate_csr_kernel<<<(N * 32 + 511) / 512, 512, 0, stream>>>(xb, packed, rowptr, AXb, N);
    } else {
        prep_kernel<<<1024, 256, 0, stream>>>(node_feat, xb, AXb, cnt, N * 8, 0, 1);
        scatter_kernel<<<2048, 256, 0, stream>>>(xb, edge_w, edge_index, AXb, E);
    }

    int nblk = (N + 63) / 64;
    gates_kernel<<<nblk, 256, 0, stream>>>(AXb, hidden, WT, bfv, outY, outH, N);
}

// Round 6
// 168.656 us; speedup vs baseline: 5.7763x; 1.1743x over previous
//
#include <hip/hip_runtime.h>
#include <hip/hip_bf16.h>
#include <math.h>

// ---------------------------------------------------------------------------
// TGCN: z/r/h GCN gates + GRU + readout.
// R1: segment_sum(w * (x@W)[src]) == segment_sum(w * x[src]) @ W
//     -> aggregate raw features ONCE (AX), fold W_g into Wl_g top half.
// R2: gate GEMMs on MFMA (bf16 in, f32 acc); weights pre-fused in d_ws.
// R3: packed bf16 atomics -> device atomic ceiling (125 dword-atomics/cy) = 85us.
// R4: bucket-LDS agg FAILED (2 blk/CU, latency-bound).
// R5: CSR (hist+scan+reorder+agg) FAILED: reorder = atomic-return + random
//     8B stores at 35% occupancy = 65us alone; 3 edge passes total.
// R6: ELL one-pass build: rank = atomicAdd(cnt[dst]) IS the slot; store {src,w}
//     at ELL[dst*16+rank]; overflow (deg>16, ~0.4% nodes) -> pk-bf16 atomic.
//     Aggregate: half-wave/node, f32 x gather, f32 regs, no LDS, full occ.
// ---------------------------------------------------------------------------

#define PAD 16

typedef __attribute__((ext_vector_type(8))) short bf16x8;   // 8 bf16 = 4 VGPR
typedef __attribute__((ext_vector_type(4))) float f32x4;    // MFMA C/D

static __device__ __forceinline__ short f2bf(float x) {
    union { float f; unsigned u; } v; v.f = x;
    unsigned r = v.u + 0x7fffu + ((v.u >> 16) & 1u);        // RNE
    return (short)(r >> 16);
}
__device__ __forceinline__ float sigmoid_(float x) { return 1.0f / (1.0f + __expf(-x)); }
__device__ __forceinline__ float tanh_(float x)    { return 1.0f - 2.0f / (__expf(2.0f * x) + 1.0f); }

// zero cnt[N] and AXb[N*64 bf16]
__global__ __launch_bounds__(256) void prep_ell_kernel(
    short* __restrict__ AXb, int* __restrict__ cnt, int N)
{
    int gid = blockIdx.x * blockDim.x + threadIdx.x;
    int stride = gridDim.x * blockDim.x;
    for (int i = gid; i < N; i += stride) cnt[i] = 0;
    const uint4 z = make_uint4(0, 0, 0, 0);
    int n16 = N * 8;                      // N*64 shorts = N*8 uint4
    for (int i = gid; i < n16; i += stride) ((uint4*)AXb)[i] = z;
}

// one thread per edge: rank via atomic, store {src,w} into ELL row; overflow
// edges (rank >= PAD) add directly into AXb via packed bf16 atomics.
__global__ __launch_bounds__(256) void build_ell_kernel(
    const int* __restrict__ ei, const float* __restrict__ ew,
    const float* __restrict__ x, int* __restrict__ cnt,
    uint2* __restrict__ ELL, short* __restrict__ AXb, int E)
{
    int i = blockIdx.x * 256 + threadIdx.x;
    if (i < E) {
        int src = ei[i];
        int dst = ei[E + i];
        float w = ew[i];
        int rank = atomicAdd(&cnt[dst], 1);
        if (rank < PAD) {
            ELL[(size_t)dst * PAD + rank] = make_uint2((unsigned)src, __float_as_uint(w));
        } else {
#pragma unroll 4
            for (int j = 0; j < 32; j++) {
                float2 xv = *(const float2*)(x + (size_t)src * 64 + j * 2);
                unsigned pk = (unsigned)(unsigned short)f2bf(xv.x * w)
                            | ((unsigned)(unsigned short)f2bf(xv.y * w) << 16);
                short* addr = AXb + (size_t)dst * 64 + j * 2;
                asm volatile("global_atomic_pk_add_bf16 %0, %1, off"
                             :: "v"(addr), "v"(pk) : "memory");
            }
        }
    }
    asm volatile("s_waitcnt vmcnt(0)" ::: "memory");
}

// half-wave per node: read <=PAD ELL slots, gather x rows (f32, coalesced
// float2 per lane), f32 register accumulate, add overflow residue, store bf16.
__global__ __launch_bounds__(512) void aggregate_ell_kernel(
    const float* __restrict__ x, const uint2* __restrict__ ELL,
    const int* __restrict__ cnt, short* __restrict__ AXb, int N)
{
    int hw = (blockIdx.x * 512 + threadIdx.x) >> 5;   // node id
    int lj = threadIdx.x & 31;                        // feature pair
    if (hw >= N) return;
    int deg = min(cnt[hw], PAD);
    const uint2* row = ELL + (size_t)hw * PAD;
    float a0 = 0.f, a1 = 0.f;
    int e = 0;
    for (; e + 1 < deg; e += 2) {
        uint2 m0 = row[e], m1 = row[e + 1];
        float2 x0 = *(const float2*)(x + (size_t)m0.x * 64 + lj * 2);
        float2 x1 = *(const float2*)(x + (size_t)m1.x * 64 + lj * 2);
        float w0 = __uint_as_float(m0.y), w1 = __uint_as_float(m1.y);
        a0 = fmaf(x0.x, w0, a0); a1 = fmaf(x0.y, w0, a1);
        a0 = fmaf(x1.x, w1, a0); a1 = fmaf(x1.y, w1, a1);
    }
    if (e < deg) {
        uint2 m = row[e];
        float2 xv = *(const float2*)(x + (size_t)m.x * 64 + lj * 2);
        float w = __uint_as_float(m.y);
        a0 = fmaf(xv.x, w, a0); a1 = fmaf(xv.y, w, a1);
    }
    // add overflow residue accumulated in AXb by build_ell
    unsigned prev = *(unsigned*)(AXb + (size_t)hw * 64 + lj * 2);
    a0 += __uint_as_float(prev << 16);
    a1 += __uint_as_float(prev & 0xffff0000u);
    unsigned pk = (unsigned)(unsigned short)f2bf(a0)
                | ((unsigned)(unsigned short)f2bf(a1) << 16);
    *(unsigned*)(AXb + (size_t)hw * 64 + lj * 2) = pk;
}

// ---- fallback path (R3): xb conversion + packed bf16 global atomics --------
__global__ __launch_bounds__(256) void prep_kernel(
    const float* __restrict__ x, short* __restrict__ xb,
    short* __restrict__ AXb, int n8)
{
    int gid = blockIdx.x * blockDim.x + threadIdx.x;
    int stride = gridDim.x * blockDim.x;
    for (int i = gid; i < n8; i += stride) {
        float4 a = ((const float4*)x)[i * 2];
        float4 b = ((const float4*)x)[i * 2 + 1];
        bf16x8 v;
        v[0] = f2bf(a.x); v[1] = f2bf(a.y); v[2] = f2bf(a.z); v[3] = f2bf(a.w);
        v[4] = f2bf(b.x); v[5] = f2bf(b.y); v[6] = f2bf(b.z); v[7] = f2bf(b.w);
        ((bf16x8*)xb)[i] = v;
        bf16x8 z = {0, 0, 0, 0, 0, 0, 0, 0};
        ((bf16x8*)AXb)[i] = z;
    }
}

__global__ __launch_bounds__(256) void scatter_kernel(
    const short* __restrict__ xb, const float* __restrict__ ew,
    const int* __restrict__ ei, short* __restrict__ AXb, int E)
{
    int hw  = (blockIdx.x * 256 + threadIdx.x) >> 5;
    int lj  = threadIdx.x & 31;
    int nhw = (gridDim.x * 256) >> 5;
    for (int e = hw; e < E; e += nhw) {
        int src = ei[e];
        int dst = ei[E + e];
        float w = ew[e];
        unsigned pv = *(const unsigned*)(xb + (size_t)src * 64 + lj * 2);
        float lo = __uint_as_float(pv << 16) * w;
        float hi = __uint_as_float(pv & 0xffff0000u) * w;
        unsigned pk = (unsigned)(unsigned short)f2bf(lo)
                    | ((unsigned)(unsigned short)f2bf(hi) << 16);
        short* addr = AXb + (size_t)dst * 64 + lj * 2;
        asm volatile("global_atomic_pk_add_bf16 %0, %1, off"
                     :: "v"(addr), "v"(pk) : "memory");
    }
    asm volatile("s_waitcnt vmcnt(0)" ::: "memory");
}

// Produces, in d_ws:
//   WT[m][64][64] bf16, n-major (transposed), m = 0..6:
//     0..2 : W_g @ Wl_g_top ; 3..5 : Wl_g_bottom ; 6 : W_out
//   bfv[4][64] f32: fused biases
__global__ __launch_bounds__(256) void fuse_weights_kernel(
    const float* __restrict__ Wz, const float* __restrict__ Wr, const float* __restrict__ Wh,
    const float* __restrict__ bz, const float* __restrict__ br, const float* __restrict__ bh,
    const float* __restrict__ Wlz, const float* __restrict__ Wlr, const float* __restrict__ Wlh,
    const float* __restrict__ blz, const float* __restrict__ blr, const float* __restrict__ blh,
    const float* __restrict__ Wout, const float* __restrict__ bout_,
    short* __restrict__ WT, float* __restrict__ bfv)
{
    int g = blockIdx.x;
    int tid = threadIdx.x;
    if (g == 3) {
        for (int i = tid; i < 4096; i += 256) {
            int k = i >> 6, n = i & 63;
            WT[6 * 4096 + n * 64 + k] = f2bf(Wout[k * 64 + n]);
        }
        if (tid < 64) bfv[192 + tid] = bout_[tid];
        return;
    }
    const float* Win = (g == 0) ? Wz : (g == 1) ? Wr : Wh;
    const float* Wl  = (g == 0) ? Wlz : (g == 1) ? Wlr : Wlh;
    const float* b   = (g == 0) ? bz : (g == 1) ? br : bh;
    const float* bl  = (g == 0) ? blz : (g == 1) ? blr : blh;

    __shared__ float wl_s[64][65];
    for (int i = tid; i < 4096; i += 256) wl_s[i >> 6][i & 63] = Wl[i];
    __syncthreads();

    int k = tid >> 2;
    int j0 = (tid & 3) << 4;
    float acc[16];
#pragma unroll
    for (int jj = 0; jj < 16; jj++) acc[jj] = 0.f;
    for (int t = 0; t < 64; t++) {
        float a = Win[k * 64 + t];
#pragma unroll
        for (int jj = 0; jj < 16; jj++) acc[jj] = fmaf(a, wl_s[t][j0 + jj], acc[jj]);
    }
#pragma unroll
    for (int jj = 0; jj < 16; jj++) WT[g * 4096 + (j0 + jj) * 64 + k] = f2bf(acc[jj]);

    for (int i = tid; i < 4096; i += 256) {
        int kk = i >> 6, n = i & 63;
        WT[(3 + g) * 4096 + n * 64 + kk] = f2bf(Wl[(64 + kk) * 64 + n]);
    }
    if (tid < 64) {
        float a2 = bl[tid];
        for (int t = 0; t < 64; t++) a2 = fmaf(b[t], wl_s[t][tid], a2);
        bfv[g * 64 + tid] = a2;
    }
}

// Fused GRU gates + readout via MFMA. 64-node tile, 4 waves.
__global__ __launch_bounds__(256, 3) void gates_kernel(
    const short* __restrict__ AXb, const float* __restrict__ hid,
    const short* __restrict__ WT, const float* __restrict__ bfv,
    float* __restrict__ outY, float* __restrict__ outH, int nNodes)
{
    __shared__ short axs[64][72];
    __shared__ short hs [64][72];
    __shared__ short rsb[64][72];
    __shared__ float hf [64][68];

    const int tid  = threadIdx.x;
    const int w    = tid >> 6;
    const int lane = tid & 63;
    const int lr   = lane & 15;
    const int lg   = lane >> 4;
    const int col  = w * 16 + lr;
    const int n0   = blockIdx.x * 64;

    {
        int row = tid >> 2;
        int c0  = (tid & 3) << 4;
        int n   = n0 + row;
        bool valid = n < nNodes;
        const float4 z4 = make_float4(0.f, 0.f, 0.f, 0.f);
        const bf16x8 zb = {0, 0, 0, 0, 0, 0, 0, 0};
        bf16x8 a0 = valid ? *(const bf16x8*)(AXb + (size_t)n * 64 + c0)     : zb;
        bf16x8 a1 = valid ? *(const bf16x8*)(AXb + (size_t)n * 64 + c0 + 8) : zb;
        *(bf16x8*)(&axs[row][c0])     = a0;
        *(bf16x8*)(&axs[row][c0 + 8]) = a1;
#pragma unroll
        for (int q = 0; q < 4; q++) {
            float4 vh = valid ? *(const float4*)(hid + (size_t)n * 64 + c0 + q * 4) : z4;
            int c = c0 + q * 4;
            hs[row][c + 0] = f2bf(vh.x); hs[row][c + 1] = f2bf(vh.y);
            hs[row][c + 2] = f2bf(vh.z); hs[row][c + 3] = f2bf(vh.w);
            hf[row][c + 0] = vh.x; hf[row][c + 1] = vh.y;
            hf[row][c + 2] = vh.z; hf[row][c + 3] = vh.w;
        }
    }

    bf16x8 wf[7][2];
#pragma unroll
    for (int m = 0; m < 7; m++)
#pragma unroll
        for (int kb = 0; kb < 2; kb++)
            wf[m][kb] = *(const bf16x8*)(WT + m * 4096 + col * 64 + kb * 32 + lg * 8);
    const float bz_ = bfv[col], br_ = bfv[64 + col], bh_ = bfv[128 + col], bo_ = bfv[192 + col];

    __syncthreads();

    const f32x4 zero4 = {0.f, 0.f, 0.f, 0.f};
    f32x4 accz[4], accr[4], acch[4];
#pragma unroll
    for (int rt = 0; rt < 4; rt++) { accz[rt] = zero4; accr[rt] = zero4; acch[rt] = zero4; }

#pragma unroll
    for (int rt = 0; rt < 4; rt++) {
        int arow = rt * 16 + lr;
#pragma unroll
        for (int kb = 0; kb < 2; kb++) {
            bf16x8 aa = *(const bf16x8*)(&axs[arow][kb * 32 + lg * 8]);
            bf16x8 ah = *(const bf16x8*)(&hs [arow][kb * 32 + lg * 8]);
            accz[rt] = __builtin_amdgcn_mfma_f32_16x16x32_bf16(aa, wf[0][kb], accz[rt], 0, 0, 0);
            accr[rt] = __builtin_amdgcn_mfma_f32_16x16x32_bf16(aa, wf[1][kb], accr[rt], 0, 0, 0);
            acch[rt] = __builtin_amdgcn_mfma_f32_16x16x32_bf16(aa, wf[2][kb], acch[rt], 0, 0, 0);
            accz[rt] = __builtin_amdgcn_mfma_f32_16x16x32_bf16(ah, wf[3][kb], accz[rt], 0, 0, 0);
            accr[rt] = __builtin_amdgcn_mfma_f32_16x16x32_bf16(ah, wf[4][kb], accr[rt], 0, 0, 0);
        }
    }

    float zf[16];
#pragma unroll
    for (int rt = 0; rt < 4; rt++) {
#pragma unroll
        for (int i = 0; i < 4; i++) {
            int row = rt * 16 + lg * 4 + i;
            float z = sigmoid_(accz[rt][i] + bz_);
            float r = sigmoid_(accr[rt][i] + br_);
            zf[rt * 4 + i] = z;
            rsb[row][col] = f2bf(r * hf[row][col]);
        }
    }
    __syncthreads();

#pragma unroll
    for (int rt = 0; rt < 4; rt++) {
        int arow = rt * 16 + lr;
#pragma unroll
        for (int kb = 0; kb < 2; kb++) {
            bf16x8 ar = *(const bf16x8*)(&rsb[arow][kb * 32 + lg * 8]);
            acch[rt] = __builtin_amdgcn_mfma_f32_16x16x32_bf16(ar, wf[5][kb], acch[rt], 0, 0, 0);
        }
    }
#pragma unroll
    for (int rt = 0; rt < 4; rt++) {
#pragma unroll
        for (int i = 0; i < 4; i++) {
            int row = rt * 16 + lg * 4 + i;
            float ht = tanh_(acch[rt][i] + bh_);
            float z  = zf[rt * 4 + i];
            float hv = z * hf[row][col] + (1.f - z) * ht;
            int n = n0 + row;
            if (n < nNodes) outH[(size_t)n * 64 + col] = hv;
            axs[row][col] = f2bf(fmaxf(hv, 0.f));
        }
    }
    __syncthreads();

    f32x4 accy[4];
#pragma unroll
    for (int rt = 0; rt < 4; rt++) accy[rt] = zero4;
#pragma unroll
    for (int rt = 0; rt < 4; rt++) {
        int arow = rt * 16 + lr;
#pragma unroll
        for (int kb = 0; kb < 2; kb++) {
            bf16x8 aa = *(const bf16x8*)(&axs[arow][kb * 32 + lg * 8]);
            accy[rt] = __builtin_amdgcn_mfma_f32_16x16x32_bf16(aa, wf[6][kb], accy[rt], 0, 0, 0);
        }
    }
#pragma unroll
    for (int rt = 0; rt < 4; rt++) {
#pragma unroll
        for (int i = 0; i < 4; i++) {
            int row = rt * 16 + lg * 4 + i;
            int n = n0 + row;
            if (n < nNodes) outY[(size_t)n * 64 + col] = accy[rt][i] + bo_;
        }
    }
}

extern "C" void kernel_launch(void* const* d_in, const int* in_sizes, int n_in,
                              void* d_out, int out_size, void* d_ws, size_t ws_size,
                              hipStream_t stream)
{
    const float* node_feat = (const float*)d_in[0];
    const float* edge_w    = (const float*)d_in[1];
    const float* hidden    = (const float*)d_in[2];
    const float* W_z  = (const float*)d_in[3];
    const float* b_z  = (const float*)d_in[4];
    const float* W_r  = (const float*)d_in[5];
    const float* b_r  = (const float*)d_in[6];
    const float* W_h  = (const float*)d_in[7];
    const float* b_h  = (const float*)d_in[8];
    const float* Wl_z = (const float*)d_in[9];
    const float* bl_z = (const float*)d_in[10];
    const float* Wl_r = (const float*)d_in[11];
    const float* bl_r = (const float*)d_in[12];
    const float* Wl_h = (const float*)d_in[13];
    const float* bl_h = (const float*)d_in[14];
    const float* W_out = (const float*)d_in[15];
    const float* b_out = (const float*)d_in[16];
    const int*   edge_index = (const int*)d_in[17];

    const int N = in_sizes[0] / 64;
    const int E = in_sizes[1];

    char* ws = (char*)d_ws;
    size_t off = 0;
    short* AXb = (short*)(ws + off); off += (size_t)N * 64 * 2;
    // union: ELL rows (ELL path) or xb (fallback path), both N*128 bytes
    char*  uni = ws + off;           off += (size_t)N * PAD * 8;
    short* WT  = (short*)(ws + off); off += 7 * 4096 * 2;
    float* bfv = (float*)(ws + off); off += 4 * 64 * 4;
    int*   cnt = (int*)(ws + off);   off += (size_t)N * 4;

    const bool useELL = (ws_size >= off) && (N <= (1 << 20));

    float* outY = (float*)d_out;                 // [N,64]
    float* outH = outY + (size_t)N * 64;         // [N,64]

    fuse_weights_kernel<<<4, 256, 0, stream>>>(W_z, W_r, W_h, b_z, b_r, b_h,
                                               Wl_z, Wl_r, Wl_h, bl_z, bl_r, bl_h,
                                               W_out, b_out, WT, bfv);
    if (useELL) {
        uint2* ELL = (uint2*)uni;
        prep_ell_kernel<<<2048, 256, 0, stream>>>(AXb, cnt, N);
        build_ell_kernel<<<(E + 255) / 256, 256, 0, stream>>>(
            edge_index, edge_w, node_feat, cnt, ELL, AXb, E);
        aggregate_ell_kernel<<<(N * 32 + 511) / 512, 512, 0, stream>>>(
            node_feat, ELL, cnt, AXb, N);
    } else {
        short* xb = (short*)uni;
        prep_kernel<<<2048, 256, 0, stream>>>(node_feat, xb, AXb, N * 8);
        scatter_kernel<<<2048, 256, 0, stream>>>(xb, edge_w, edge_index, AXb, E);
    }

    int nblk = (N + 63) / 64;
    gates_kernel<<<nblk, 256, 0, stream>>>(AXb, hidden, WT, bfv, outY, outH, N);
}